// Round 1
// 240.666 us; speedup vs baseline: 1.2945x; 1.2945x over previous
//
#include <hip/hip_runtime.h>
#include <cstddef>

// StreamingISTFT fully fused: denorm+pack -> FFT32(k2) -> LDS -> FFT32(k1)
// -> window -> LDS frame tile -> overlap-add -> coalesced stores.
// B=8, F=1024(+Nyquist), T=2048, HOP=512, L=2048.
// irfft(2048) = complex IFFT(1024) (real-packing); IFFT(1024) = 32x32 four-step.
//
// R7: single-kernel fusion. OLA identity: contribution of frames[l][t] goes to
// out[512*t + l]; all 4 contributors to an output share l mod 64 -> a block
// owning all 1024 freqs for an 8-wide t-tile completes the OLA locally.
// Tile-boundary output columns (rel 0..2, 8..10) get partial sums from two
// adjacent blocks -> coalesced atomicAdd onto memset-zeroed output.
//
// R8: XCD-aware work remap. rocprof showed FETCH_SIZE = 446 MB vs 134 MB of
// input (3.2x over-fetch): each block reads only 32 B per 8 KB row, so each
// 128 B line is split across 4 adjacent t-tiles -- which the default grid
// round-robins onto 4 *different* XCD L2s. Remap (1D grid, id%8 = xcd) so
// each XCD owns 32 contiguous t-tiles (256 contiguous columns) of one batch:
// line sharing now happens inside one L2 (2 MB group working set, 2 groups
// co-resident = 4 MB = L2). Bijective map -> correctness independent of the
// actual dispatch->XCD policy.
//
// LDS 67.6 KB -> 2 blocks/CU; X-tile strides (k1:264, r:8, t:1) give exactly
// 2-way (free) banks on both stage-1 writes and stage-2 reads; frame tile
// stride 2053 keeps OLA reads conflict-free.

#define TDIM 2048
#define FDIM 1024
#define TT 8                    // t-columns per block
#define NTOT (512 * 2048)       // output samples per batch

static constexpr int kBREV[32] = {0,16,8,24,4,20,12,28,2,18,10,26,6,22,14,30,
                                  1,17,9,25,5,21,13,29,3,19,11,27,7,23,15,31};
// e^{+2*pi*i*r/32}, r=0..15 (inverse-transform sign)
static constexpr float kTR[16] = {
  1.0f, 0.98078528040323044f, 0.92387953251128674f, 0.83146961230254524f,
  0.70710678118654757f, 0.55557023301960218f, 0.38268343236508978f, 0.19509032201612825f,
  0.0f, -0.19509032201612825f, -0.38268343236508978f, -0.55557023301960218f,
  -0.70710678118654757f, -0.83146961230254524f, -0.92387953251128674f, -0.98078528040323044f};
static constexpr float kTI[16] = {
  0.0f, 0.19509032201612825f, 0.38268343236508978f, 0.55557023301960218f,
  0.70710678118654757f, 0.83146961230254524f, 0.92387953251128674f, 0.98078528040323044f,
  1.0f, 0.98078528040323044f, 0.92387953251128674f, 0.83146961230254524f,
  0.70710678118654757f, 0.55557023301960218f, 0.38268343236508978f, 0.19509032201612825f};

// One radix-2 stage, half-span H; literal indices after specialization -> SROA.
template <int H>
__device__ __forceinline__ void fft32_stage(float ar[32], float ai[32]) {
  constexpr int TSTEP = 16 / H;
  #pragma unroll
  for (int g = 0; g < 32; g += 2 * H) {
    #pragma unroll
    for (int j = 0; j < H; ++j) {
      const float twr = kTR[j * TSTEP];
      const float twi = kTI[j * TSTEP];
      const int i0 = g + j, i1 = i0 + H;
      const float tr = twr * ar[i1] - twi * ai[i1];
      const float ti = twr * ai[i1] + twi * ar[i1];
      ar[i1] = ar[i0] - tr; ai[i1] = ai[i0] - ti;
      ar[i0] += tr;         ai[i0] += ti;
    }
  }
}

// In-register radix-2 DIT FFT32 (inverse sign). Input bit-reversed; out natural.
__device__ __forceinline__ void ifft32_core(float ar[32], float ai[32]) {
  fft32_stage<1>(ar, ai);
  fft32_stage<2>(ar, ai);
  fft32_stage<4>(ar, ai);
  fft32_stage<8>(ar, ai);
  fft32_stage<16>(ar, ai);
}

// |v|^(2*PE) * KS via native v_log_f32 + v_exp_f32. v=0 -> 0: ok.
__device__ __forceinline__ float pow_gain(float v, float PE, float KS) {
  return KS * __builtin_amdgcn_exp2f(PE * __builtin_amdgcn_logf(v));
}

// X-tile layout: X(t, k1, r) = k1*264 + r*8 + t  (264 = 32*8 + 8 pad).
// Stage-1 write lanes (t,k1): bank = (8k1 + t + 8r) -> 2-way. Stage-2 read
// lanes (t,r): bank = (8r + t + 8k1) -> 2-way. Max index 8439 < 8448.
#define XIDX(t, k1, r) ((k1) * 264 + (r) * 8 + (t))
#define FSTR 2053               // frame tile row stride (odd -> spread banks)

__global__ __launch_bounds__(256) void istft_fused(const float* __restrict__ in,
                                                   const float* __restrict__ invw,
                                                   float* __restrict__ out) {
  __shared__ float buf[16896];          // 67.6 KB; X uses [0,16896), F reuses [0,16419)
  float* Xr = buf;
  float* Xi = buf + 8448;

  const int tid = threadIdx.x;
  const int tl  = tid & 7;              // t within tile
  const int q   = tid >> 3;             // k1 (stage 1) / r (stage 2)

  // XCD-aware remap: hardware round-robins linear block id across the 8 XCDs
  // (id%8). Give XCD x a contiguous run of 32 t-tiles of one batch so the
  // 128B-line sharing between adjacent tiles stays inside one L2.
  const int id   = blockIdx.x;          // 0..2047
  const int xcd  = id & 7;
  const int slot = id >> 3;             // 0..255, increments over time per XCD
  const int b    = slot >> 5;           // 0..7  (batch; 32 consecutive slots)
  const int tile = xcd * 32 + (slot & 31);  // 0..255
  const int t0   = tile * TT;
  const int t    = t0 + tl;

  const float* re_p = in + ((size_t)b * 2 + 0) * ((size_t)FDIM * TDIM);
  const float* im_p = in + ((size_t)b * 2 + 1) * ((size_t)FDIM * TDIM);

  const float KS = (float)(exp((-1.0 / 0.65) * log(0.06)) / 2048.0);
  const float PE = 7.0f / 26.0f;

  // ---- Stage 1: denorm + Hermitian pack + FFT32 over k2 + twiddle -> X ----
  {
    float ar[32], ai[32];
    #pragma unroll
    for (int k2 = 0; k2 < 32; ++k2) {
      const int k  = q + 32 * k2;
      const int km = (1024 - k) & 1023;
      const float x1 = re_p[(size_t)k  * TDIM + t];
      const float y1 = im_p[(size_t)k  * TDIM + t];
      const float x2 = re_p[(size_t)km * TDIM + t];
      const float y2 = im_p[(size_t)km * TDIM + t];
      const float g1 = pow_gain(x1 * x1 + y1 * y1, PE, KS);
      const float g2 = pow_gain(x2 * x2 + y2 * y2, PE, KS);
      const float s1r = x1 * g1, s1i = y1 * g1;
      const float s2r = x2 * g2, s2i = y2 * g2;
      // W[k] = (S1 + conj(S2)) + i*T*(S1 - conj(S2)),  T = e^{i pi k/1024}
      const float ang = 3.0679615757712824e-3f * (float)k;
      const float sn = __sinf(ang), cs = __cosf(ang);
      const float Pre = s1r + s2r, Pim = s1i - s2i;
      const float Qre = s1r - s2r, Qim = s1i + s2i;
      const float u = cs * Qim + sn * Qre;
      const float v = cs * Qre - sn * Qim;
      float wr = Pre - u, wi = Pim + v;
      if (q == 0 && k2 == 0) { wr = s1r; wi = s1r; }  // DC: Im dropped, Nyquist=0
      ar[kBREV[k2]] = wr; ai[kBREV[k2]] = wi;
    }
    ifft32_core(ar, ai);
    #pragma unroll
    for (int r = 0; r < 32; ++r) {      // inter-stage twiddle e^{2 pi i k1 r/1024}
      const float ang = 6.1359231515425649e-3f * (float)(q * r);
      const float sn = __sinf(ang), cs = __cosf(ang);
      Xr[XIDX(tl, q, r)] = cs * ar[r] - sn * ai[r];
      Xi[XIDX(tl, q, r)] = cs * ai[r] + sn * ar[r];
    }
  }
  __syncthreads();

  // ---- Stage 2: FFT32 over k1 -> z; window; frame tile F[t][l] ----
  {
    float zr[32], zi[32];
    #pragma unroll
    for (int i = 0; i < 32; ++i) {      // bit-reversed k1 load order
      zr[i] = Xr[XIDX(tl, kBREV[i], q)];
      zi[i] = Xi[XIDX(tl, kBREV[i], q)];
    }
    __syncthreads();                    // all X reads done before F overwrites buf
    ifft32_core(zr, zi);
    #pragma unroll
    for (int s = 0; s < 32; ++s) {
      const int m  = q + 32 * s;
      const int l0 = 2 * m;
      buf[tl * FSTR + l0]     = zr[s] * invw[l0];
      buf[tl * FSTR + l0 + 1] = zi[s] * invw[l0 + 1];
    }
  }
  __syncthreads();

  // ---- OLA: out[512*t' + j] = sum_c F[t'-c-t0][j + 512c] ----
  float* ob = out + (size_t)b * NTOT;
  for (int rel = 0; rel < 11; ++rel) {
    const int tp = t0 + rel;
    if (tp > 2047) break;
    #pragma unroll
    for (int half = 0; half < 2; ++half) {
      const int j = tid + 256 * half;   // lanes j-consecutive -> coalesced
      float v = 0.0f;
      #pragma unroll
      for (int c = 0; c < 4; ++c) {
        const int tt = rel - c;
        if (tt >= 0 && tt < TT) v += buf[tt * FSTR + j + 512 * c];
      }
      const int n = tp * 512 + j;
      if (rel >= 3 && rel <= 7) ob[n] = v;          // all 4 contributors in-block
      else atomicAdd(&ob[n], v);                     // tile boundary: 2 writers
    }
  }
}

extern "C" void kernel_launch(void* const* d_in, const int* in_sizes, int n_in,
                              void* d_out, int out_size, void* d_ws, size_t ws_size,
                              hipStream_t stream) {
  (void)in_sizes; (void)n_in; (void)d_ws; (void)ws_size;
  const float* in   = (const float*)d_in[0];
  const float* invw = (const float*)d_in[1];
  float* out = (float*)d_out;
  hipMemsetAsync(out, 0, (size_t)out_size * sizeof(float), stream);
  istft_fused<<<dim3(TDIM / TT * 8), 256, 0, stream>>>(in, invw, out);
}